// Round 8
// baseline (221.370 us; speedup 1.0000x reference)
//
#include <hip/hip_runtime.h>

#define S_LEN 4096
#define EMBD  1024
#define HEADD 64

typedef __bf16 bf16x8 __attribute__((ext_vector_type(8)));
typedef float  f32x4  __attribute__((ext_vector_type(4)));

__device__ __forceinline__ unsigned short f2bf(float f) {
  union { float f; unsigned u; } x; x.f = f;
  unsigned r = x.u + 0x7FFFu + ((x.u >> 16) & 1u);
  return (unsigned short)(r >> 16);
}

__device__ __forceinline__ bf16x8 cvt8(f32x4 a, f32x4 b) {
  union { bf16x8 v; unsigned short s[8]; } u;
#pragma unroll
  for (int j = 0; j < 4; j++) { u.s[j] = f2bf(a[j]); u.s[4 + j] = f2bf(b[j]); }
  return u.v;
}

__device__ __forceinline__ unsigned fbits(float f) {
  union { float f; unsigned u; } x; x.f = f; return x.u;
}

// ---------------- Kernel 0: W transpose/convert + bias; fold scale*log2e into Q ----
__global__ void prep_w(const float* __restrict__ Wk, const float* __restrict__ bk,
                       const float* __restrict__ Wq, const float* __restrict__ bq,
                       const float* __restrict__ Wv, const float* __restrict__ bv,
                       unsigned short* __restrict__ wt, float* __restrict__ bias) {
  int n = blockIdx.x;            // 0..191 : [0,64)=K, [64,128)=Q(scaled), [128,192)=V
  int t = threadIdx.x;
  const float QSCALE = 0.125f * 1.44269504088896340736f;  // 1/sqrt(64) * log2(e)
  const float* W; const float* bsrc; int col; float s = 1.0f;
  if (n < 64)       { W = Wk; bsrc = bk; col = n; }
  else if (n < 128) { W = Wq; bsrc = bq; col = n - 64; s = QSCALE; }
  else              { W = Wv; bsrc = bv; col = n - 128; }
  for (int k = t; k < EMBD; k += 256)
    wt[n * EMBD + k] = f2bf(W[k * HEADD + col] * s);
  if (t == 0) bias[n] = bsrc[col] * s;
}

// ---------------- Kernel 1: QKV projection, stage-free, N-split across waves -------
// 1024 blocks x 256 thr (4 waves), 4 blocks/CU (16 waves/CU = 4/SIMD, VGPR<=128).
// Block = 16 X rows; wave w = cols [48w, 48w+48). X f32 read directly with 4-deep
// rotating prefetch (static idx); W ping-pong 1 step ahead; no LDS, no barriers.
// Per-SIMD the 4 resident waves share one W slice -> L1-hot.
__global__ __launch_bounds__(256, 4) void proj_qkv(
    const float* __restrict__ X, const unsigned short* __restrict__ wt,
    const float* __restrict__ bias,
    unsigned short* __restrict__ qws, unsigned short* __restrict__ kws,
    unsigned short* __restrict__ vtws) {
  const int w = threadIdx.x >> 6;
  const int lane = threadIdx.x & 63;
  const int l15 = lane & 15, lg = lane >> 4;
  const int row0 = blockIdx.x * 16;
  const float* xp = X + (size_t)(row0 + l15) * EMBD + lg * 8;
  const unsigned short* wp = wt + (size_t)(w * 48 + l15) * EMBD + lg * 8;

  f32x4 acc[3];
#pragma unroll
  for (int j = 0; j < 3; j++) acc[j] = (f32x4){0.f, 0.f, 0.f, 0.f};

  f32x4 xa[4], xb[4];
#pragma unroll
  for (int i = 0; i < 4; i++) {
    xa[i] = *(const f32x4*)(xp + i * 32);
    xb[i] = *(const f32x4*)(xp + i * 32 + 4);
  }
  bf16x8 wf[2][3];
#pragma unroll
  for (int j = 0; j < 3; j++) wf[0][j] = *(const bf16x8*)(wp + (size_t)j * 16 * EMBD);

#pragma unroll
  for (int s = 0; s < 32; s++) {
    if (s + 1 < 32) {
#pragma unroll
      for (int j = 0; j < 3; j++)
        wf[(s + 1) & 1][j] = *(const bf16x8*)(wp + (size_t)j * 16 * EMBD + (s + 1) * 32);
    }
    const bf16x8 a = cvt8(xa[s & 3], xb[s & 3]);
    if (s + 4 < 32) {
      xa[s & 3] = *(const f32x4*)(xp + (s + 4) * 32);
      xb[s & 3] = *(const f32x4*)(xp + (s + 4) * 32 + 4);
    }
#pragma unroll
    for (int j = 0; j < 3; j++)
      acc[j] = __builtin_amdgcn_mfma_f32_16x16x32_bf16(a, wf[s & 1][j], acc[j], 0, 0, 0);
  }

  // ---- epilogue: wave w owns N-frags 3w..3w+2 ----
  const int crow0 = row0 + lg * 4;
#pragma unroll
  for (int j = 0; j < 3; j++) {
    const int nf = w * 3 + j;
    const int n = nf * 16 + l15;
    const float bs = bias[n];
    if (nf < 8) {
      unsigned short* dst = (nf < 4) ? kws : qws;
      const int nn = n & 63;
#pragma unroll
      for (int i = 0; i < 4; i++)
        dst[(size_t)(crow0 + i) * HEADD + nn] = f2bf(acc[j][i] + bs);
    } else {
      const int d = n - 128;
      const int bb = crow0 >> 12, sr = crow0 & 4095;
      union { unsigned long long pk; unsigned short s[4]; } u;
#pragma unroll
      for (int i = 0; i < 4; i++) u.s[i] = f2bf(acc[j][i] + bs);
      *(unsigned long long*)&vtws[((size_t)bb * HEADD + d) * S_LEN + sr] = u.pk;
    }
  }
}

// ---------------- Kernel 2: causal flash attention ---------------------------------
// 256 blocks x 1024 thr (16 waves, kv-split-16) = 4 waves/SIMD (VGPR forced <=128,
// same count the compiler already chose in R7). Each WAVE carries FOUR 16-row
// q-groups: heavy pair (pH=127-x) + light pair (pL=x); uniform 65-tile blocks.
__global__ __launch_bounds__(1024, 4) void attn(
    const unsigned short* __restrict__ qws,
    const unsigned short* __restrict__ kws,
    const unsigned short* __restrict__ vtws,
    float* __restrict__ out) {
  __shared__ unsigned short pl[16][16][72];  // per-wave P bounce (36.9 KB)
  __shared__ float obuf[15][16][16][4];      // partials, nd-contiguous (61.4 KB)
  __shared__ float mbuf[16][16], lbuf[16][16];

  const int w = threadIdx.x >> 6;
  const int lane = threadIdx.x & 63;
  const int l15 = lane & 15, lg = lane >> 4;

  const int b = blockIdx.x & 3;              // batch -> XCDs {b, b+4}
  const int x = blockIdx.x >> 2;             // 0..63
  const int pH = 127 - x, pL = x;
  const int qbH = pH << 5, qbL = pL << 5;
  const int tlH = pH >> 1, tlL = pL >> 1;    // diagonal kv-tiles (tlL < tlH)

  const unsigned short* kb = kws + (size_t)b * S_LEN * HEADD;
  const unsigned short* vb = vtws + (size_t)b * HEADD * S_LEN;
  const unsigned short* qp = qws + (size_t)b * S_LEN * HEADD;

  const unsigned short* qA = qp + (size_t)(qbH + l15) * HEADD + lg * 8;
  const unsigned short* qB = qp + (size_t)(qbH + 16 + l15) * HEADD + lg * 8;
  const unsigned short* qC = qp + (size_t)(qbL + l15) * HEADD + lg * 8;
  const unsigned short* qD = qp + (size_t)(qbL + 16 + l15) * HEADD + lg * 8;
  const bf16x8 bqA0 = *(const bf16x8*)qA, bqA1 = *(const bf16x8*)(qA + 32);
  const bf16x8 bqB0 = *(const bf16x8*)qB, bqB1 = *(const bf16x8*)(qB + 32);
  const bf16x8 bqC0 = *(const bf16x8*)qC, bqC1 = *(const bf16x8*)(qC + 32);
  const bf16x8 bqD0 = *(const bf16x8*)qD, bqD1 = *(const bf16x8*)(qD + 32);

  f32x4 oA[4], oB[4], oC[4], oD[4];
#pragma unroll
  for (int nd = 0; nd < 4; nd++) {
    oA[nd] = (f32x4){0.f, 0.f, 0.f, 0.f};
    oB[nd] = (f32x4){0.f, 0.f, 0.f, 0.f};
    oC[nd] = (f32x4){0.f, 0.f, 0.f, 0.f};
    oD[nd] = (f32x4){0.f, 0.f, 0.f, 0.f};
  }
  float mA = -3.0e38f, lA = 0.f, mB = -3.0e38f, lB = 0.f;
  float mC = -3.0e38f, lC = 0.f, mD = -3.0e38f, lD = 0.f;

#define PROC(BQ0, BQ1, O, M, LL, QB, TLX, tt)                                   \
  do {                                                                          \
    f32x4 sc[4];                                                                \
    __builtin_amdgcn_s_setprio(1);                                              \
    _Pragma("unroll")                                                           \
    for (int nf = 0; nf < 4; nf++) {                                            \
      f32x4 z = (f32x4){0.f, 0.f, 0.f, 0.f};                                    \
      z = __builtin_amdgcn_mfma_f32_16x16x32_bf16(k0[nf], BQ0, z, 0, 0, 0);     \
      sc[nf] = __builtin_amdgcn_mfma_f32_16x16x32_bf16(k1[nf], BQ1, z, 0, 0, 0);\
    }                                                                           \
    __builtin_amdgcn_s_setprio(0);                                              \
    if ((tt) == (TLX)) {                                                        \
      const int qa = (QB) + l15;                                                \
      _Pragma("unroll")                                                         \
      for (int nf = 0; nf < 4; nf++)                                            \
        _Pragma("unroll")                                                       \
        for (int i = 0; i < 4; i++)                                             \
          if ((tt) * 64 + nf * 16 + lg * 4 + i > qa) sc[nf][i] = -1.0e30f;      \
    }                                                                           \
    float pm = sc[0][0];                                                        \
    _Pragma("unroll")                                                           \
    for (int nf = 0; nf < 4; nf++)                                              \
      _Pragma("unroll")                                                         \
      for (int i = 0; i < 4; i++) pm = fmaxf(pm, sc[nf][i]);                    \
    if (!__all(pm <= M + 8.0f)) {                                               \
      float mx = fmaxf(pm, __shfl_xor(pm, 16));                                 \
      mx = fmaxf(mx, __shfl_xor(mx, 32));                                       \
      const float mn = fmaxf(M, mx);                                            \
      const float al = __builtin_amdgcn_exp2f(M - mn);                          \
      M = mn;                                                                   \
      LL *= al;                                                                 \
      float alr[4];                                                             \
      _Pragma("unroll")                                                         \
      for (int i = 0; i < 4; i++) alr[i] = __shfl(al, lg * 4 + i);              \
      _Pragma("unroll")                                                         \
      for (int nd = 0; nd < 4; nd++)                                            \
        _Pragma("unroll")                                                       \
        for (int i = 0; i < 4; i++) O[nd][i] *= alr[i];                         \
    }                                                                           \
    _Pragma("unroll")                                                           \
    for (int nf = 0; nf < 4; nf++) {                                            \
      f32x4 p;                                                                  \
      _Pragma("unroll")                                                         \
      for (int i = 0; i < 4; i++) p[i] = __builtin_amdgcn_exp2f(sc[nf][i] - M); \
      LL += p[0] + p[1] + p[2] + p[3];                                          \
      unsigned lo_ = __builtin_amdgcn_perm(fbits(p[1]) + 0x8000u,               \
                                           fbits(p[0]) + 0x8000u, 0x07060302u); \
      unsigned hi_ = __builtin_amdgcn_perm(fbits(p[3]) + 0x8000u,               \
                                           fbits(p[2]) + 0x8000u, 0x07060302u); \
      uint2 pk_; pk_.x = lo_; pk_.y = hi_;                                      \
      *(uint2*)&pl[w][l15][nf * 16 + lg * 4] = pk_;                             \
    }                                                                           \
    const bf16x8 ap0 = *(const bf16x8*)&pl[w][l15][lg * 8];                     \
    const bf16x8 ap1 = *(const bf16x8*)&pl[w][l15][32 + lg * 8];                \
    __builtin_amdgcn_s_setprio(1);                                              \
    _Pragma("unroll")                                                           \
    for (int nd = 0; nd < 4; nd++) {                                            \
      f32x4 oo = __builtin_amdgcn_mfma_f32_16x16x32_bf16(ap0, v0[nd], O[nd], 0, 0, 0); \
      O[nd] = __builtin_amdgcn_mfma_f32_16x16x32_bf16(ap1, v1[nd], oo, 0, 0, 0);\
    }                                                                           \
    __builtin_amdgcn_s_setprio(0);                                              \
  } while (0)

#pragma unroll 1
  for (int t = w; t <= tlH; t += 16) {
    bf16x8 k0[4], k1[4], v0[4], v1[4];
    {
      const unsigned short* kt = kb + ((size_t)t * 64 + l15) * HEADD + lg * 8;
      const unsigned short* vt = vb + (size_t)l15 * S_LEN + t * 64 + lg * 8;
#pragma unroll
      for (int nf = 0; nf < 4; nf++) {
        k0[nf] = *(const bf16x8*)(kt + (size_t)nf * 16 * HEADD);
        k1[nf] = *(const bf16x8*)(kt + (size_t)nf * 16 * HEADD + 32);
        v0[nf] = *(const bf16x8*)(vt + (size_t)nf * 16 * S_LEN);
        v1[nf] = *(const bf16x8*)(vt + (size_t)nf * 16 * S_LEN + 32);
      }
    }
    PROC(bqA0, bqA1, oA, mA, lA, qbH, tlH, t);
    PROC(bqB0, bqB1, oB, mB, lB, qbH + 16, tlH, t);
    if (t <= tlL) {
      PROC(bqC0, bqC1, oC, mC, lC, qbL, tlL, t);
      PROC(bqD0, bqD1, oD, mD, lD, qbL + 16, tlL, t);
    }
  }
#undef PROC

  // ---- merge the 16 kv-splits, one group at a time (obuf reused) ----
#define MERGEG(O, M, LL, QB)                                                    \
  do {                                                                          \
    LL += __shfl_xor(LL, 16);                                                   \
    LL += __shfl_xor(LL, 32);                                                   \
    if (lane < 16) { mbuf[w][lane] = M; lbuf[w][lane] = LL; }                   \
    if (w > 0) {                                                                \
      _Pragma("unroll")                                                         \
      for (int i = 0; i < 4; i++) {                                             \
        f32x4 v;                                                                \
        _Pragma("unroll")                                                       \
        for (int nd = 0; nd < 4; nd++) v[nd] = O[nd][i];                        \
        *(f32x4*)&obuf[w - 1][lg * 4 + i][l15][0] = v;                          \
      }                                                                         \
    }                                                                           \
    __syncthreads();                                                            \
    if (w == 0) {                                                               \
      _Pragma("unroll")                                                         \
      for (int i = 0; i < 4; i++) {                                             \
        const int r = lg * 4 + i;                                               \
        float M16 = mbuf[0][r];                                                 \
        _Pragma("unroll")                                                       \
        for (int k = 1; k < 16; k++) M16 = fmaxf(M16, mbuf[k][r]);              \
        float a0 = __builtin_amdgcn_exp2f(mbuf[0][r] - M16);                    \
        float Lt = a0 * lbuf[0][r];                                             \
        f32x4 val;                                                              \
        _Pragma("unroll")                                                       \
        for (int nd = 0; nd < 4; nd++) val[nd] = O[nd][i] * a0;                 \
        _Pragma("unroll")                                                       \
        for (int k = 1; k < 16; k++) {                                          \
          const float ak = __builtin_amdgcn_exp2f(mbuf[k][r] - M16);            \
          Lt += ak * lbuf[k][r];                                                \
          const f32x4 v = *(const f32x4*)&obuf[k - 1][r][l15][0];               \
          _Pragma("unroll")                                                     \
          for (int nd = 0; nd < 4; nd++) val[nd] += v[nd] * ak;                 \
        }                                                                       \
        const float iL = 1.0f / Lt;                                             \
        _Pragma("unroll")                                                       \
        for (int nd = 0; nd < 4; nd++)                                          \
          out[((size_t)b * S_LEN + (QB) + r) * HEADD + nd * 16 + l15] = val[nd] * iL; \
      }                                                                         \
    }                                                                           \
    __syncthreads();                                                            \
  } while (0)

  MERGEG(oA, mA, lA, qbH);
  MERGEG(oB, mB, lB, qbH + 16);
  MERGEG(oC, mC, lC, qbL);
  MERGEG(oD, mD, lD, qbL + 16);
#undef MERGEG
}

extern "C" void kernel_launch(void* const* d_in, const int* in_sizes, int n_in,
                              void* d_out, int out_size, void* d_ws, size_t ws_size,
                              hipStream_t stream) {
  const float* X  = (const float*)d_in[0];
  const float* Wk = (const float*)d_in[1];
  const float* bk = (const float*)d_in[2];
  const float* Wq = (const float*)d_in[3];
  const float* bq = (const float*)d_in[4];
  const float* Wv = (const float*)d_in[5];
  const float* bv = (const float*)d_in[6];
  float* out = (float*)d_out;

  char* ws = (char*)d_ws;
  unsigned short* kws  = (unsigned short*)(ws);                      // 2 MB
  unsigned short* qws  = (unsigned short*)(ws + (2u << 20));         // 2 MB
  unsigned short* vtws = (unsigned short*)(ws + (4u << 20));         // 2 MB (transposed)
  unsigned short* wt   = (unsigned short*)(ws + (6u << 20));         // 384 KB
  float*          bias = (float*)(ws + (6u << 20) + (512u << 10));   // 768 B

  prep_w<<<dim3(192), dim3(256), 0, stream>>>(Wk, bk, Wq, bq, Wv, bv, wt, bias);
  proj_qkv<<<dim3(1024), dim3(256), 0, stream>>>(X, wt, bias, qws, kws, vtws);
  attn<<<dim3(256), dim3(1024), 0, stream>>>(qws, kws, vtws, out);
}

// Round 9
// 141.361 us; speedup vs baseline: 1.5660x; 1.5660x over previous
//
#include <hip/hip_runtime.h>

#define S_LEN 4096
#define EMBD  1024
#define HEADD 64

typedef __bf16 bf16x8 __attribute__((ext_vector_type(8)));
typedef float  f32x4  __attribute__((ext_vector_type(4)));

__device__ __forceinline__ unsigned short f2bf(float f) {
  union { float f; unsigned u; } x; x.f = f;
  unsigned r = x.u + 0x7FFFu + ((x.u >> 16) & 1u);
  return (unsigned short)(r >> 16);
}

__device__ __forceinline__ bf16x8 cvt8(f32x4 a, f32x4 b) {
  union { bf16x8 v; unsigned short s[8]; } u;
#pragma unroll
  for (int j = 0; j < 4; j++) { u.s[j] = f2bf(a[j]); u.s[4 + j] = f2bf(b[j]); }
  return u.v;
}

__device__ __forceinline__ unsigned fbits(float f) {
  union { float f; unsigned u; } x; x.f = f; return x.u;
}

// ---------------- Kernel 0: W transpose/convert + bias; fold scale*log2e into Q ----
__global__ void prep_w(const float* __restrict__ Wk, const float* __restrict__ bk,
                       const float* __restrict__ Wq, const float* __restrict__ bq,
                       const float* __restrict__ Wv, const float* __restrict__ bv,
                       unsigned short* __restrict__ wt, float* __restrict__ bias) {
  int n = blockIdx.x;            // 0..191 : [0,64)=K, [64,128)=Q(scaled), [128,192)=V
  int t = threadIdx.x;
  const float QSCALE = 0.125f * 1.44269504088896340736f;  // 1/sqrt(64) * log2(e)
  const float* W; const float* bsrc; int col; float s = 1.0f;
  if (n < 64)       { W = Wk; bsrc = bk; col = n; }
  else if (n < 128) { W = Wq; bsrc = bq; col = n - 64; s = QSCALE; }
  else              { W = Wv; bsrc = bv; col = n - 128; }
  for (int k = t; k < EMBD; k += 256)
    wt[n * EMBD + k] = f2bf(W[k * HEADD + col] * s);
  if (t == 0) bias[n] = bsrc[col] * s;
}

// ---------------- Kernel 1: QKV projection, LDS-staged X (16-row blocks) -----------
// 1024 blocks x 256 thr (4 waves), 4 blocks/CU (LDS 32KB, VGPR<=128) = 4 waves/SIMD.
// Simple R6-style loop (batched variants measured slower). Wave w owns 3 N-frags.
__global__ __launch_bounds__(256, 4) void proj_qkv(
    const float* __restrict__ X, const unsigned short* __restrict__ wt,
    const float* __restrict__ bias,
    unsigned short* __restrict__ qws, unsigned short* __restrict__ kws,
    unsigned short* __restrict__ vtws) {
  __shared__ unsigned short xs[16 * 1024];   // 32 KB, XOR-swizzled 16B slots

  const int tid = threadIdx.x;
  const int w = tid >> 6;
  const int lane = tid & 63;
  const int l15 = lane & 15, lg = lane >> 4;
  const int row0 = blockIdx.x * 16;

  // ---- stage X (f32 HBM, coalesced) -> LDS bf16, swizzled ----
#pragma unroll
  for (int it = 0; it < 8; it++) {
    const int u = it * 256 + tid;            // 0..2047
    const int r = u >> 7;                    // 0..15
    const int c = (u & 127) * 8;             // 0..1016
    const f32x4 a  = *(const f32x4*)(X + (size_t)(row0 + r) * EMBD + c);
    const f32x4 b2 = *(const f32x4*)(X + (size_t)(row0 + r) * EMBD + c + 4);
    int soff = (r << 10) + c;
    soff ^= (r & 7) << 3;                    // 16B-slot XOR swizzle
    *(bf16x8*)&xs[soff] = cvt8(a, b2);
  }
  __syncthreads();

  // ---- compute: wave w owns N-frags w*3 .. w*3+2 over 16 rows ----
  f32x4 acc[3];
#pragma unroll
  for (int j = 0; j < 3; j++) acc[j] = (f32x4){0.f, 0.f, 0.f, 0.f};

  const unsigned short* wp = wt + (size_t)(w * 48 + l15) * EMBD + lg * 8;

#pragma unroll 4
  for (int s = 0; s < 32; s++) {
    const int c = s * 32 + lg * 8;
    int so0 = (l15 << 10) + c; so0 ^= (l15 & 7) << 3;
    const bf16x8 a0 = *(const bf16x8*)&xs[so0];
#pragma unroll
    for (int j = 0; j < 3; j++) {
      const bf16x8 bf = *(const bf16x8*)(wp + (size_t)j * 16 * EMBD + s * 32);
      acc[j] = __builtin_amdgcn_mfma_f32_16x16x32_bf16(a0, bf, acc[j], 0, 0, 0);
    }
  }

  // ---- epilogue ----
  const int crow0 = row0 + lg * 4;
#pragma unroll
  for (int j = 0; j < 3; j++) {
    const int nf = w * 3 + j;
    const int n = nf * 16 + l15;
    const float bs = bias[n];
    if (nf < 8) {
      unsigned short* dst = (nf < 4) ? kws : qws;
      const int nn = n & 63;
#pragma unroll
      for (int i = 0; i < 4; i++)
        dst[(size_t)(crow0 + i) * HEADD + nn] = f2bf(acc[j][i] + bs);
    } else {
      const int d = n - 128;
      const int bb = crow0 >> 12, sr = crow0 & 4095;
      union { unsigned long long pk; unsigned short s[4]; } u;
#pragma unroll
      for (int i = 0; i < 4; i++) u.s[i] = f2bf(acc[j][i] + bs);
      *(unsigned long long*)&vtws[((size_t)bb * HEADD + d) * S_LEN + sr] = u.pk;
    }
  }
}

// ---------------- Kernel 2: causal flash attention ---------------------------------
// 512 blocks x 512 thr (8 waves, kv-split-8), 2 blocks/CU = 4 waves/SIMD.
// Each WAVE carries TWO 16-row q-groups (H = 255-x, L = x): uniform ~64 PROCs per
// block; per-wave register need ~ R6's (compiled to 84 VGPR) so the (512,4) cap
// is safe. Every K/V tile load feeds up to 2 PROCs.
__global__ __launch_bounds__(512, 4) void attn(
    const unsigned short* __restrict__ qws,
    const unsigned short* __restrict__ kws,
    const unsigned short* __restrict__ vtws,
    float* __restrict__ out) {
  __shared__ unsigned short pl[8][16][72];   // per-wave P bounce (18.4 KB)
  __shared__ float obuf[7][16][16][4];       // partials, nd-contiguous (28.7 KB)
  __shared__ float mbuf[8][16], lbuf[8][16];

  const int w = threadIdx.x >> 6;
  const int lane = threadIdx.x & 63;
  const int l15 = lane & 15, lg = lane >> 4;

  const int b = blockIdx.x & 3;              // batch
  const int x = blockIdx.x >> 2;             // 0..127
  const int pH = 255 - x, pL = x;
  const int qbH = pH << 4, qbL = pL << 4;
  const int tlH = pH >> 2, tlL = pL >> 2;    // diagonal kv-tiles (tlL < tlH)

  const unsigned short* kb = kws + (size_t)b * S_LEN * HEADD;
  const unsigned short* vb = vtws + (size_t)b * HEADD * S_LEN;
  const unsigned short* qp = qws + (size_t)b * S_LEN * HEADD;

  const unsigned short* qA = qp + (size_t)(qbH + l15) * HEADD + lg * 8;
  const unsigned short* qC = qp + (size_t)(qbL + l15) * HEADD + lg * 8;
  const bf16x8 bqH0 = *(const bf16x8*)qA, bqH1 = *(const bf16x8*)(qA + 32);
  const bf16x8 bqL0 = *(const bf16x8*)qC, bqL1 = *(const bf16x8*)(qC + 32);

  f32x4 oH[4], oL[4];
#pragma unroll
  for (int nd = 0; nd < 4; nd++) {
    oH[nd] = (f32x4){0.f, 0.f, 0.f, 0.f};
    oL[nd] = (f32x4){0.f, 0.f, 0.f, 0.f};
  }
  float mH = -3.0e38f, lH = 0.f, mL = -3.0e38f, lL = 0.f;

#define PROC(BQ0, BQ1, O, M, LL, QB, TLX, tt)                                   \
  do {                                                                          \
    f32x4 sc[4];                                                                \
    __builtin_amdgcn_s_setprio(1);                                              \
    _Pragma("unroll")                                                           \
    for (int nf = 0; nf < 4; nf++) {                                            \
      f32x4 z = (f32x4){0.f, 0.f, 0.f, 0.f};                                    \
      z = __builtin_amdgcn_mfma_f32_16x16x32_bf16(k0[nf], BQ0, z, 0, 0, 0);     \
      sc[nf] = __builtin_amdgcn_mfma_f32_16x16x32_bf16(k1[nf], BQ1, z, 0, 0, 0);\
    }                                                                           \
    __builtin_amdgcn_s_setprio(0);                                              \
    if ((tt) == (TLX)) {                                                        \
      const int qa = (QB) + l15;                                                \
      _Pragma("unroll")                                                         \
      for (int nf = 0; nf < 4; nf++)                                            \
        _Pragma("unroll")                                                       \
        for (int i = 0; i < 4; i++)                                             \
          if ((tt) * 64 + nf * 16 + lg * 4 + i > qa) sc[nf][i] = -1.0e30f;      \
    }                                                                           \
    float pm = sc[0][0];                                                        \
    _Pragma("unroll")                                                           \
    for (int nf = 0; nf < 4; nf++)                                              \
      _Pragma("unroll")                                                         \
      for (int i = 0; i < 4; i++) pm = fmaxf(pm, sc[nf][i]);                    \
    if (!__all(pm <= M + 8.0f)) {                                               \
      float mx = fmaxf(pm, __shfl_xor(pm, 16));                                 \
      mx = fmaxf(mx, __shfl_xor(mx, 32));                                       \
      const float mn = fmaxf(M, mx);                                            \
      const float al = __builtin_amdgcn_exp2f(M - mn);                          \
      M = mn;                                                                   \
      LL *= al;                                                                 \
      float alr[4];                                                             \
      _Pragma("unroll")                                                         \
      for (int i = 0; i < 4; i++) alr[i] = __shfl(al, lg * 4 + i);              \
      _Pragma("unroll")                                                         \
      for (int nd = 0; nd < 4; nd++)                                            \
        _Pragma("unroll")                                                       \
        for (int i = 0; i < 4; i++) O[nd][i] *= alr[i];                         \
    }                                                                           \
    _Pragma("unroll")                                                           \
    for (int nf = 0; nf < 4; nf++) {                                            \
      f32x4 p;                                                                  \
      _Pragma("unroll")                                                         \
      for (int i = 0; i < 4; i++) p[i] = __builtin_amdgcn_exp2f(sc[nf][i] - M); \
      LL += p[0] + p[1] + p[2] + p[3];                                          \
      unsigned lo_ = __builtin_amdgcn_perm(fbits(p[1]) + 0x8000u,               \
                                           fbits(p[0]) + 0x8000u, 0x07060302u); \
      unsigned hi_ = __builtin_amdgcn_perm(fbits(p[3]) + 0x8000u,               \
                                           fbits(p[2]) + 0x8000u, 0x07060302u); \
      uint2 pk_; pk_.x = lo_; pk_.y = hi_;                                      \
      *(uint2*)&pl[w][l15][nf * 16 + lg * 4] = pk_;                             \
    }                                                                           \
    const bf16x8 ap0 = *(const bf16x8*)&pl[w][l15][lg * 8];                     \
    const bf16x8 ap1 = *(const bf16x8*)&pl[w][l15][32 + lg * 8];                \
    __builtin_amdgcn_s_setprio(1);                                              \
    _Pragma("unroll")                                                           \
    for (int nd = 0; nd < 4; nd++) {                                            \
      f32x4 oo = __builtin_amdgcn_mfma_f32_16x16x32_bf16(ap0, v0[nd], O[nd], 0, 0, 0); \
      O[nd] = __builtin_amdgcn_mfma_f32_16x16x32_bf16(ap1, v1[nd], oo, 0, 0, 0);\
    }                                                                           \
    __builtin_amdgcn_s_setprio(0);                                              \
  } while (0)

#pragma unroll 1
  for (int t = w; t <= tlH; t += 8) {
    bf16x8 k0[4], k1[4], v0[4], v1[4];
    {
      const unsigned short* kt = kb + ((size_t)t * 64 + l15) * HEADD + lg * 8;
      const unsigned short* vt = vb + (size_t)l15 * S_LEN + t * 64 + lg * 8;
#pragma unroll
      for (int nf = 0; nf < 4; nf++) {
        k0[nf] = *(const bf16x8*)(kt + (size_t)nf * 16 * HEADD);
        k1[nf] = *(const bf16x8*)(kt + (size_t)nf * 16 * HEADD + 32);
        v0[nf] = *(const bf16x8*)(vt + (size_t)nf * 16 * S_LEN);
        v1[nf] = *(const bf16x8*)(vt + (size_t)nf * 16 * S_LEN + 32);
      }
    }
    PROC(bqH0, bqH1, oH, mH, lH, qbH, tlH, t);
    if (t <= tlL) PROC(bqL0, bqL1, oL, mL, lL, qbL, tlL, t);
  }
#undef PROC

  // ---- merge the 8 kv-splits, one group at a time (obuf reused) ----
#define MERGEG(O, M, LL, QB)                                                    \
  do {                                                                          \
    LL += __shfl_xor(LL, 16);                                                   \
    LL += __shfl_xor(LL, 32);                                                   \
    if (lane < 16) { mbuf[w][lane] = M; lbuf[w][lane] = LL; }                   \
    if (w > 0) {                                                                \
      _Pragma("unroll")                                                         \
      for (int i = 0; i < 4; i++) {                                             \
        f32x4 v;                                                                \
        _Pragma("unroll")                                                       \
        for (int nd = 0; nd < 4; nd++) v[nd] = O[nd][i];                        \
        *(f32x4*)&obuf[w - 1][lg * 4 + i][l15][0] = v;                          \
      }                                                                         \
    }                                                                           \
    __syncthreads();                                                            \
    if (w == 0) {                                                               \
      _Pragma("unroll")                                                         \
      for (int i = 0; i < 4; i++) {                                             \
        const int r = lg * 4 + i;                                               \
        float M8 = mbuf[0][r];                                                  \
        _Pragma("unroll")                                                       \
        for (int k = 1; k < 8; k++) M8 = fmaxf(M8, mbuf[k][r]);                 \
        float a0 = __builtin_amdgcn_exp2f(mbuf[0][r] - M8);                     \
        float Lt = a0 * lbuf[0][r];                                             \
        f32x4 val;                                                              \
        _Pragma("unroll")                                                       \
        for (int nd = 0; nd < 4; nd++) val[nd] = O[nd][i] * a0;                 \
        _Pragma("unroll")                                                       \
        for (int k = 1; k < 8; k++) {                                           \
          const float ak = __builtin_amdgcn_exp2f(mbuf[k][r] - M8);             \
          Lt += ak * lbuf[k][r];                                                \
          const f32x4 v = *(const f32x4*)&obuf[k - 1][r][l15][0];               \
          _Pragma("unroll")                                                     \
          for (int nd = 0; nd < 4; nd++) val[nd] += v[nd] * ak;                 \
        }                                                                       \
        const float iL = 1.0f / Lt;                                             \
        _Pragma("unroll")                                                       \
        for (int nd = 0; nd < 4; nd++)                                          \
          out[((size_t)b * S_LEN + (QB) + r) * HEADD + nd * 16 + l15] = val[nd] * iL; \
      }                                                                         \
    }                                                                           \
    __syncthreads();                                                            \
  } while (0)

  MERGEG(oH, mH, lH, qbH);
  MERGEG(oL, mL, lL, qbL);
#undef MERGEG
}

extern "C" void kernel_launch(void* const* d_in, const int* in_sizes, int n_in,
                              void* d_out, int out_size, void* d_ws, size_t ws_size,
                              hipStream_t stream) {
  const float* X  = (const float*)d_in[0];
  const float* Wk = (const float*)d_in[1];
  const float* bk = (const float*)d_in[2];
  const float* Wq = (const float*)d_in[3];
  const float* bq = (const float*)d_in[4];
  const float* Wv = (const float*)d_in[5];
  const float* bv = (const float*)d_in[6];
  float* out = (float*)d_out;

  char* ws = (char*)d_ws;
  unsigned short* kws  = (unsigned short*)(ws);                      // 2 MB
  unsigned short* qws  = (unsigned short*)(ws + (2u << 20));         // 2 MB
  unsigned short* vtws = (unsigned short*)(ws + (4u << 20));         // 2 MB (transposed)
  unsigned short* wt   = (unsigned short*)(ws + (6u << 20));         // 384 KB
  float*          bias = (float*)(ws + (6u << 20) + (512u << 10));   // 768 B

  prep_w<<<dim3(192), dim3(256), 0, stream>>>(Wk, bk, Wq, bq, Wv, bv, wt, bias);
  proj_qkv<<<dim3(1024), dim3(256), 0, stream>>>(X, wt, bias, qws, kws, vtws);
  attn<<<dim3(512), dim3(512), 0, stream>>>(qws, kws, vtws, out);
}

// Round 10
// 115.646 us; speedup vs baseline: 1.9142x; 1.2224x over previous
//
#include <hip/hip_runtime.h>

#define S_LEN 4096
#define EMBD  1024
#define HEADD 64

typedef __bf16 bf16x8 __attribute__((ext_vector_type(8)));
typedef float  f32x4  __attribute__((ext_vector_type(4)));

__device__ __forceinline__ unsigned short f2bf(float f) {
  union { float f; unsigned u; } x; x.f = f;
  unsigned r = x.u + 0x7FFFu + ((x.u >> 16) & 1u);
  return (unsigned short)(r >> 16);
}

__device__ __forceinline__ bf16x8 cvt8(f32x4 a, f32x4 b) {
  union { bf16x8 v; unsigned short s[8]; } u;
#pragma unroll
  for (int j = 0; j < 4; j++) { u.s[j] = f2bf(a[j]); u.s[4 + j] = f2bf(b[j]); }
  return u.v;
}

__device__ __forceinline__ unsigned fbits(float f) {
  union { float f; unsigned u; } x; x.f = f; return x.u;
}

// ---------------- Kernel 0: W transpose/convert + bias; fold scale*log2e into Q ----
__global__ void prep_w(const float* __restrict__ Wk, const float* __restrict__ bk,
                       const float* __restrict__ Wq, const float* __restrict__ bq,
                       const float* __restrict__ Wv, const float* __restrict__ bv,
                       unsigned short* __restrict__ wt, float* __restrict__ bias) {
  int n = blockIdx.x;            // 0..191 : [0,64)=K, [64,128)=Q(scaled), [128,192)=V
  int t = threadIdx.x;
  const float QSCALE = 0.125f * 1.44269504088896340736f;  // 1/sqrt(64) * log2(e)
  const float* W; const float* bsrc; int col; float s = 1.0f;
  if (n < 64)       { W = Wk; bsrc = bk; col = n; }
  else if (n < 128) { W = Wq; bsrc = bq; col = n - 64; s = QSCALE; }
  else              { W = Wv; bsrc = bv; col = n - 128; }
  for (int k = t; k < EMBD; k += 256)
    wt[n * EMBD + k] = f2bf(W[k * HEADD + col] * s);
  if (t == 0) bias[n] = bsrc[col] * s;
}

// ---------------- Kernel 1: QKV projection, LDS-staged X (32-row blocks) -----------
// 512 blocks x 512 thr (8 waves), launch_bounds(512,2) = 2 blocks/CU (CUDA
// semantics: arg2 = min BLOCKS/CU) -> 16 waves/CU = 4/SIMD, VGPR cap 128.
// Wave w: rows rg=w&1 (16 rows), cols nh=w>>1 (48 cols = 3 N-frags).
// W L2 traffic = 512 x 384 KB = 192 MB (~6 us aggregate L2).
__global__ __launch_bounds__(512, 2) void proj_qkv(
    const float* __restrict__ X, const unsigned short* __restrict__ wt,
    const float* __restrict__ bias,
    unsigned short* __restrict__ qws, unsigned short* __restrict__ kws,
    unsigned short* __restrict__ vtws) {
  __shared__ unsigned short xs[32 * 1024];   // 64 KB, XOR-swizzled 16B slots

  const int tid = threadIdx.x;
  const int w = tid >> 6;
  const int lane = tid & 63;
  const int l15 = lane & 15, lg = lane >> 4;
  const int rg = w & 1, nh = w >> 1;
  const int row0 = blockIdx.x * 32;

  // ---- stage X (f32 HBM, coalesced) -> LDS bf16, swizzled ----
#pragma unroll
  for (int it = 0; it < 8; it++) {
    const int u = it * 512 + tid;            // 0..4095
    const int r = u >> 7;                    // 0..31
    const int c = (u & 127) * 8;             // 0..1016
    const f32x4 a  = *(const f32x4*)(X + (size_t)(row0 + r) * EMBD + c);
    const f32x4 b2 = *(const f32x4*)(X + (size_t)(row0 + r) * EMBD + c + 4);
    int soff = (r << 10) + c;
    soff ^= (r & 7) << 3;                    // 16B-slot XOR swizzle
    *(bf16x8*)&xs[soff] = cvt8(a, b2);
  }
  __syncthreads();

  // ---- compute: wave (rg, nh): N-frags nh*3..nh*3+2 over rows rg*16..rg*16+15 ----
  f32x4 acc[3];
#pragma unroll
  for (int j = 0; j < 3; j++) acc[j] = (f32x4){0.f, 0.f, 0.f, 0.f};

  const unsigned short* wp = wt + (size_t)(nh * 48 + l15) * EMBD + lg * 8;

#pragma unroll 4
  for (int s = 0; s < 32; s++) {
    const int c = s * 32 + lg * 8;
    const int r = rg * 16 + l15;
    int so0 = (r << 10) + c; so0 ^= (r & 7) << 3;
    const bf16x8 a0 = *(const bf16x8*)&xs[so0];
#pragma unroll
    for (int j = 0; j < 3; j++) {
      const bf16x8 bf = *(const bf16x8*)(wp + (size_t)j * 16 * EMBD + s * 32);
      acc[j] = __builtin_amdgcn_mfma_f32_16x16x32_bf16(a0, bf, acc[j], 0, 0, 0);
    }
  }

  // ---- epilogue ----
  const int crow0 = row0 + rg * 16 + lg * 4;
#pragma unroll
  for (int j = 0; j < 3; j++) {
    const int nf = nh * 3 + j;
    const int n = nf * 16 + l15;
    const float bs = bias[n];
    if (nf < 8) {
      unsigned short* dst = (nf < 4) ? kws : qws;
      const int nn = n & 63;
#pragma unroll
      for (int i = 0; i < 4; i++)
        dst[(size_t)(crow0 + i) * HEADD + nn] = f2bf(acc[j][i] + bs);
    } else {
      const int d = n - 128;
      const int bb = crow0 >> 12, sr = crow0 & 4095;
      union { unsigned long long pk; unsigned short s[4]; } u;
#pragma unroll
      for (int i = 0; i < 4; i++) u.s[i] = f2bf(acc[j][i] + bs);
      *(unsigned long long*)&vtws[((size_t)bb * HEADD + d) * S_LEN + sr] = u.pk;
    }
  }
}

// ---------------- Kernel 2: causal flash attention ---------------------------------
// 512 blocks x 512 thr (8 waves, kv-split-8), launch_bounds(512,2) = 2 blocks/CU
// -> 16 waves/CU = 4 waves/SIMD with the 128-VGPR cap (R7 proved no spill at 128).
// Each WAVE carries TWO 16-row q-groups (H = 255-x, L = x): uniform work.
__global__ __launch_bounds__(512, 2) void attn(
    const unsigned short* __restrict__ qws,
    const unsigned short* __restrict__ kws,
    const unsigned short* __restrict__ vtws,
    float* __restrict__ out) {
  __shared__ unsigned short pl[8][16][72];   // per-wave P bounce (18.4 KB)
  __shared__ float obuf[7][16][16][4];       // partials, nd-contiguous (28.7 KB)
  __shared__ float mbuf[8][16], lbuf[8][16];

  const int w = threadIdx.x >> 6;
  const int lane = threadIdx.x & 63;
  const int l15 = lane & 15, lg = lane >> 4;

  const int b = blockIdx.x & 3;              // batch
  const int x = blockIdx.x >> 2;             // 0..127
  const int pH = 255 - x, pL = x;
  const int qbH = pH << 4, qbL = pL << 4;
  const int tlH = pH >> 2, tlL = pL >> 2;    // diagonal kv-tiles (tlL < tlH)

  const unsigned short* kb = kws + (size_t)b * S_LEN * HEADD;
  const unsigned short* vb = vtws + (size_t)b * HEADD * S_LEN;
  const unsigned short* qp = qws + (size_t)b * S_LEN * HEADD;

  const unsigned short* qA = qp + (size_t)(qbH + l15) * HEADD + lg * 8;
  const unsigned short* qC = qp + (size_t)(qbL + l15) * HEADD + lg * 8;
  const bf16x8 bqH0 = *(const bf16x8*)qA, bqH1 = *(const bf16x8*)(qA + 32);
  const bf16x8 bqL0 = *(const bf16x8*)qC, bqL1 = *(const bf16x8*)(qC + 32);

  f32x4 oH[4], oL[4];
#pragma unroll
  for (int nd = 0; nd < 4; nd++) {
    oH[nd] = (f32x4){0.f, 0.f, 0.f, 0.f};
    oL[nd] = (f32x4){0.f, 0.f, 0.f, 0.f};
  }
  float mH = -3.0e38f, lH = 0.f, mL = -3.0e38f, lL = 0.f;

#define PROC(BQ0, BQ1, O, M, LL, QB, TLX, tt)                                   \
  do {                                                                          \
    f32x4 sc[4];                                                                \
    __builtin_amdgcn_s_setprio(1);                                              \
    _Pragma("unroll")                                                           \
    for (int nf = 0; nf < 4; nf++) {                                            \
      f32x4 z = (f32x4){0.f, 0.f, 0.f, 0.f};                                    \
      z = __builtin_amdgcn_mfma_f32_16x16x32_bf16(k0[nf], BQ0, z, 0, 0, 0);     \
      sc[nf] = __builtin_amdgcn_mfma_f32_16x16x32_bf16(k1[nf], BQ1, z, 0, 0, 0);\
    }                                                                           \
    __builtin_amdgcn_s_setprio(0);                                              \
    if ((tt) == (TLX)) {                                                        \
      const int qa = (QB) + l15;                                                \
      _Pragma("unroll")                                                         \
      for (int nf = 0; nf < 4; nf++)                                            \
        _Pragma("unroll")                                                       \
        for (int i = 0; i < 4; i++)                                             \
          if ((tt) * 64 + nf * 16 + lg * 4 + i > qa) sc[nf][i] = -1.0e30f;      \
    }                                                                           \
    float pm = sc[0][0];                                                        \
    _Pragma("unroll")                                                           \
    for (int nf = 0; nf < 4; nf++)                                              \
      _Pragma("unroll")                                                         \
      for (int i = 0; i < 4; i++) pm = fmaxf(pm, sc[nf][i]);                    \
    if (!__all(pm <= M + 8.0f)) {                                               \
      float mx = fmaxf(pm, __shfl_xor(pm, 16));                                 \
      mx = fmaxf(mx, __shfl_xor(mx, 32));                                       \
      const float mn = fmaxf(M, mx);                                            \
      const float al = __builtin_amdgcn_exp2f(M - mn);                          \
      M = mn;                                                                   \
      LL *= al;                                                                 \
      float alr[4];                                                             \
      _Pragma("unroll")                                                         \
      for (int i = 0; i < 4; i++) alr[i] = __shfl(al, lg * 4 + i);              \
      _Pragma("unroll")                                                         \
      for (int nd = 0; nd < 4; nd++)                                            \
        _Pragma("unroll")                                                       \
        for (int i = 0; i < 4; i++) O[nd][i] *= alr[i];                         \
    }                                                                           \
    _Pragma("unroll")                                                           \
    for (int nf = 0; nf < 4; nf++) {                                            \
      f32x4 p;                                                                  \
      _Pragma("unroll")                                                         \
      for (int i = 0; i < 4; i++) p[i] = __builtin_amdgcn_exp2f(sc[nf][i] - M); \
      LL += p[0] + p[1] + p[2] + p[3];                                          \
      unsigned lo_ = __builtin_amdgcn_perm(fbits(p[1]) + 0x8000u,               \
                                           fbits(p[0]) + 0x8000u, 0x07060302u); \
      unsigned hi_ = __builtin_amdgcn_perm(fbits(p[3]) + 0x8000u,               \
                                           fbits(p[2]) + 0x8000u, 0x07060302u); \
      uint2 pk_; pk_.x = lo_; pk_.y = hi_;                                      \
      *(uint2*)&pl[w][l15][nf * 16 + lg * 4] = pk_;                             \
    }                                                                           \
    const bf16x8 ap0 = *(const bf16x8*)&pl[w][l15][lg * 8];                     \
    const bf16x8 ap1 = *(const bf16x8*)&pl[w][l15][32 + lg * 8];                \
    __builtin_amdgcn_s_setprio(1);                                              \
    _Pragma("unroll")                                                           \
    for (int nd = 0; nd < 4; nd++) {                                            \
      f32x4 oo = __builtin_amdgcn_mfma_f32_16x16x32_bf16(ap0, v0[nd], O[nd], 0, 0, 0); \
      O[nd] = __builtin_amdgcn_mfma_f32_16x16x32_bf16(ap1, v1[nd], oo, 0, 0, 0);\
    }                                                                           \
    __builtin_amdgcn_s_setprio(0);                                              \
  } while (0)

#pragma unroll 1
  for (int t = w; t <= tlH; t += 8) {
    bf16x8 k0[4], k1[4], v0[4], v1[4];
    {
      const unsigned short* kt = kb + ((size_t)t * 64 + l15) * HEADD + lg * 8;
      const unsigned short* vt = vb + (size_t)l15 * S_LEN + t * 64 + lg * 8;
#pragma unroll
      for (int nf = 0; nf < 4; nf++) {
        k0[nf] = *(const bf16x8*)(kt + (size_t)nf * 16 * HEADD);
        k1[nf] = *(const bf16x8*)(kt + (size_t)nf * 16 * HEADD + 32);
        v0[nf] = *(const bf16x8*)(vt + (size_t)nf * 16 * S_LEN);
        v1[nf] = *(const bf16x8*)(vt + (size_t)nf * 16 * S_LEN + 32);
      }
    }
    PROC(bqH0, bqH1, oH, mH, lH, qbH, tlH, t);
    if (t <= tlL) PROC(bqL0, bqL1, oL, mL, lL, qbL, tlL, t);
  }
#undef PROC

  // ---- merge the 8 kv-splits, one group at a time (obuf reused) ----
#define MERGEG(O, M, LL, QB)                                                    \
  do {                                                                          \
    LL += __shfl_xor(LL, 16);                                                   \
    LL += __shfl_xor(LL, 32);                                                   \
    if (lane < 16) { mbuf[w][lane] = M; lbuf[w][lane] = LL; }                   \
    if (w > 0) {                                                                \
      _Pragma("unroll")                                                         \
      for (int i = 0; i < 4; i++) {                                             \
        f32x4 v;                                                                \
        _Pragma("unroll")                                                       \
        for (int nd = 0; nd < 4; nd++) v[nd] = O[nd][i];                        \
        *(f32x4*)&obuf[w - 1][lg * 4 + i][l15][0] = v;                          \
      }                                                                         \
    }                                                                           \
    __syncthreads();                                                            \
    if (w == 0) {                                                               \
      _Pragma("unroll")                                                         \
      for (int i = 0; i < 4; i++) {                                             \
        const int r = lg * 4 + i;                                               \
        float M8 = mbuf[0][r];                                                  \
        _Pragma("unroll")                                                       \
        for (int k = 1; k < 8; k++) M8 = fmaxf(M8, mbuf[k][r]);                 \
        float a0 = __builtin_amdgcn_exp2f(mbuf[0][r] - M8);                     \
        float Lt = a0 * lbuf[0][r];                                             \
        f32x4 val;                                                              \
        _Pragma("unroll")                                                       \
        for (int nd = 0; nd < 4; nd++) val[nd] = O[nd][i] * a0;                 \
        _Pragma("unroll")                                                       \
        for (int k = 1; k < 8; k++) {                                           \
          const float ak = __builtin_amdgcn_exp2f(mbuf[k][r] - M8);             \
          Lt += ak * lbuf[k][r];                                                \
          const f32x4 v = *(const f32x4*)&obuf[k - 1][r][l15][0];               \
          _Pragma("unroll")                                                     \
          for (int nd = 0; nd < 4; nd++) val[nd] += v[nd] * ak;                 \
        }                                                                       \
        const float iL = 1.0f / Lt;                                             \
        _Pragma("unroll")                                                       \
        for (int nd = 0; nd < 4; nd++)                                          \
          out[((size_t)b * S_LEN + (QB) + r) * HEADD + nd * 16 + l15] = val[nd] * iL; \
      }                                                                         \
    }                                                                           \
    __syncthreads();                                                            \
  } while (0)

  MERGEG(oH, mH, lH, qbH);
  MERGEG(oL, mL, lL, qbL);
#undef MERGEG
}

extern "C" void kernel_launch(void* const* d_in, const int* in_sizes, int n_in,
                              void* d_out, int out_size, void* d_ws, size_t ws_size,
                              hipStream_t stream) {
  const float* X  = (const float*)d_in[0];
  const float* Wk = (const float*)d_in[1];
  const float* bk = (const float*)d_in[2];
  const float* Wq = (const float*)d_in[3];
  const float* bq = (const float*)d_in[4];
  const float* Wv = (const float*)d_in[5];
  const float* bv = (const float*)d_in[6];
  float* out = (float*)d_out;

  char* ws = (char*)d_ws;
  unsigned short* kws  = (unsigned short*)(ws);                      // 2 MB
  unsigned short* qws  = (unsigned short*)(ws + (2u << 20));         // 2 MB
  unsigned short* vtws = (unsigned short*)(ws + (4u << 20));         // 2 MB (transposed)
  unsigned short* wt   = (unsigned short*)(ws + (6u << 20));         // 384 KB
  float*          bias = (float*)(ws + (6u << 20) + (512u << 10));   // 768 B

  prep_w<<<dim3(192), dim3(256), 0, stream>>>(Wk, bk, Wq, bq, Wv, bv, wt, bias);
  proj_qkv<<<dim3(512), dim3(512), 0, stream>>>(X, wt, bias, qws, kws, vtws);
  attn<<<dim3(512), dim3(512), 0, stream>>>(qws, kws, vtws, out);
}